// Round 13
// baseline (132.457 us; speedup 1.0000x reference)
//
#include <hip/hip_runtime.h>

#define BN 4
#define LN 1024
#define SN 1024
#define HN 8
#define EN 64
#define OFF_ATT (BN * LN * HN * EN)
#define OFF_ENT (OFF_ATT + BN * HN * LN * SN)

// workspace byte offsets (need ~25 MB)
#define WS_MW 0u                          // f16 mask, 8*1024*1024*2 = 16 MB
#define WS_KB 16777216u                   // bf16 K, 4 MB
#define WS_VT (WS_KB + 4194304u)          // bf16 V^T, 4 MB

// per-wave LDS region: 16 rows x pitch 272 B (att bf16, then V-partial f32)
#define WPITCH 272
#define WREG 4352

typedef __attribute__((ext_vector_type(8))) __bf16 bf16x8;
typedef __attribute__((ext_vector_type(4))) float f32x4;
typedef __attribute__((ext_vector_type(2))) float f32x2;
typedef __attribute__((ext_vector_type(4))) unsigned int uint4v;
typedef __attribute__((ext_vector_type(2))) unsigned int uint2v;
typedef __attribute__((ext_vector_type(4))) _Float16 f16x4;

// blockIdx.x encodes (lbHi, b, lbLo): batch-siblings of an (h,l-tile) are 8
// blocks apart -> same XCD under round-robin -> shared mw slices L2-hot.
__device__ __forceinline__ void decode_block(int x, int& b, int& lb) {
  int lbLo = x & 7;
  b = (x >> 3) & 3;
  lb = (x >> 5) * 8 + lbLo;
}

// 8 consecutive floats -> packed bf16 hi + lo (trunc split)
__device__ __forceinline__ void cvt8(const float* p, uint4v& hv, uint4v& lv) {
  float4 a = *(const float4*)p;
  float4 bq = *(const float4*)(p + 4);
  float x[8] = {a.x, a.y, a.z, a.w, bq.x, bq.y, bq.z, bq.w};
  unsigned int h[8], lo[8];
#pragma unroll
  for (int i = 0; i < 8; ++i) {
    unsigned int ub = __float_as_uint(x[i]);
    h[i] = ub >> 16;
    float lf = x[i] - __uint_as_float(ub & 0xffff0000u);
    lo[i] = __float_as_uint(lf) >> 16;
  }
  hv = uint4v{h[0] | (h[1] << 16), h[2] | (h[3] << 16),
              h[4] | (h[5] << 16), h[6] | (h[7] << 16)};
  lv = uint4v{lo[0] | (lo[1] << 16), lo[2] | (lo[3] << 16),
              lo[4] | (lo[5] << 16), lo[6] | (lo[7] << 16)};
}

__device__ __forceinline__ uint4v pack8_trunc(float4 a, float4 b) {
  return uint4v{(__float_as_uint(a.x) >> 16) | (__float_as_uint(a.y) & 0xffff0000u),
                (__float_as_uint(a.z) >> 16) | (__float_as_uint(a.w) & 0xffff0000u),
                (__float_as_uint(b.x) >> 16) | (__float_as_uint(b.y) & 0xffff0000u),
                (__float_as_uint(b.z) >> 16) | (__float_as_uint(b.w) & 0xffff0000u)};
}

// ---------------- fused prep kernel (mask + K + V^T) ----------------
// blocks [0,8192): phi-mask f16; [8192,9216): K->bf16; [9216,10240): V->vT.
__global__ __launch_bounds__(256) void k_prep(
    const float* __restrict__ kk, const float* __restrict__ vv,
    const float* __restrict__ phi, const float* __restrict__ u,
    const float* __restrict__ p_logtau, const float* __restrict__ p_thresh,
    _Float16* __restrict__ mw, unsigned short* __restrict__ kb,
    unsigned short* __restrict__ vT) {
  const int bx = blockIdx.x;
  if (bx < 8192) {
    const float tau = fminf(fmaxf(__expf(p_logtau[0]), 0.1f), 5.0f);
    const float rtau = 1.0f / tau;
    const float thr = fminf(fmaxf(p_thresh[0], 0.01f), 0.99f);
    int idx = (bx * 256 + threadIdx.x) * 4;
    float4 u4 = *(const float4*)(u + idx);
    float4 p4 = *(const float4*)(phi + idx);
    float uu[4] = {u4.x, u4.y, u4.z, u4.w};
    float pp[4] = {p4.x, p4.y, p4.z, p4.w};
    f16x4 o;
#pragma unroll
    for (int i = 0; i < 4; ++i) {
      float g = __logf(__fdividef(uu[i] + 1e-8f, 1.0f - uu[i] + 1e-8f));
      float z = (g + pp[i]) * rtau;
      float sig = __fdividef(1.0f, 1.0f + __expf(-z));
      o[i] = (_Float16)(-10000.0f * fmaxf(thr - sig, 0.0f) * 0.125f);
    }
    *(f16x4*)(mw + idx) = o;
  } else if (bx < 9216) {
    int gid = (bx - 8192) * 256 + threadIdx.x;
    int e8 = gid & 7;
    int tmp = gid >> 3;
    int h = tmp & 7;
    int bs = tmp >> 3;
    int s = bs & 1023;
    int b = bs >> 10;
    const float* src = kk + (size_t)gid * 8;
    float4 a = *(const float4*)src;
    float4 bq = *(const float4*)(src + 4);
    *(uint4v*)(kb + (((size_t)(b * 8 + h) * 1024 + s) * 64) + e8 * 8) =
        pack8_trunc(a, bq);
  } else {
    int gid = (bx - 9216) * 256 + threadIdx.x;
    int s8 = gid & 127;
    int t1 = gid >> 7;
    int e = t1 & 63;
    int t2 = t1 >> 6;
    int h = t2 & 7;
    int b = t2 >> 3;
    float x[8];
#pragma unroll
    for (int j = 0; j < 8; ++j)
      x[j] = vv[((size_t)(b * 1024 + s8 * 8 + j) * 8 + h) * 64 + e];
    uint4v pv = pack8_trunc(float4{x[0], x[1], x[2], x[3]},
                            float4{x[4], x[5], x[6], x[7]});
    *(uint4v*)(vT + ((size_t)(b * 8 + h) * 64 + e) * 1024 + s8 * 8) = pv;
  }
}

// ---------------- fused scores + mask + softmax + entropy + PV ----------------
// Block = 8 waves (512 thr), 16 q-rows of one (b,h). TWO barriers total;
// everything else is wave-private so waves drift out of phase and the
// VALU/VMEM/LDS/MFMA pipes overlap across waves (R12 showed lockstep phases
// time-slice the pipes: occupancy 2x gave 0 gain).
// Wave w owns s in [w*128, w*128+128). Swapped QK^T (D=K*Q): lane (cl,cg)
// owns q-row l=lb*16+cl, s = w*128 + tg*16 + cg*4..+3, accs[8].
// Softmax: per-wave (m_w, Z_w, E_w) -> bar1 -> online merge with e^{m_w-M}.
// PV: wave-private att-bf16 tile [16 x 128] in own LDS region (no barrier),
// partial PV over own s-slice for ALL 64 e (16 MFMAs), partials overwrite
// own region -> bar2 -> 8-way reduce + NT V store.
__global__ __launch_bounds__(512, 2) void k_fused(
    const float* __restrict__ q, const unsigned short* __restrict__ kb,
    const unsigned short* __restrict__ vT, const _Float16* __restrict__ mw,
    const float* __restrict__ pos, const int* __restrict__ p_causal,
    float* __restrict__ out) {
  int b, lb;
  decode_block(blockIdx.x, b, lb);
  const int h = blockIdx.y;
  const int tid = threadIdx.x;
  const int w = __builtin_amdgcn_readfirstlane(tid >> 6);  // 0..7
  const int c = tid & 63;
  const int cl = c & 15;
  const int cg = c >> 4;

  __shared__ __align__(16) unsigned char lds_wav[8 * WREG];      // 34.8 KB
  __shared__ float redM[8][16], redZ[8][16], redE[8][16];

  const int causal = p_causal[0];
  const int l = lb * 16 + cl;  // this lane's q-row
  const float* posb = pos + b * LN;
  const unsigned short* kbb = kb + ((size_t)(b * 8 + h) * 1024) * 64;

  // ---- Q fragments (B operand): n = cl (q-row), k = cg*8+j
  uint4v qh[2], ql[2];
#pragma unroll
  for (int cc = 0; cc < 2; ++cc) {
    const float* qp = q + (((size_t)b * LN + l) * HN + h) * EN + cc * 32 + cg * 8;
    cvt8(qp, qh[cc], ql[cc]);
  }

  f32x4 accs[8];

  // ---- QK^T: 2 batches of 4 tiles (8 loads in flight, then 16 MFMAs)
#pragma unroll
  for (int tgb = 0; tgb < 2; ++tgb) {
    uint4v kf[4][2];
#pragma unroll
    for (int t2 = 0; t2 < 4; ++t2)
#pragma unroll
      for (int cc = 0; cc < 2; ++cc)
        kf[t2][cc] = *(const uint4v*)(kbb +
                                      (size_t)(w * 128 + (tgb * 4 + t2) * 16 + cl) * 64 +
                                      cc * 32 + cg * 8);
#pragma unroll
    for (int t2 = 0; t2 < 4; ++t2) {
      f32x4 acc = f32x4{0.f, 0.f, 0.f, 0.f};
#pragma unroll
      for (int cc = 0; cc < 2; ++cc) {
        bf16x8 kv = __builtin_bit_cast(bf16x8, kf[t2][cc]);
        acc = __builtin_amdgcn_mfma_f32_16x16x32_bf16(
            kv, __builtin_bit_cast(bf16x8, qh[cc]), acc, 0, 0, 0);
        acc = __builtin_amdgcn_mfma_f32_16x16x32_bf16(
            kv, __builtin_bit_cast(bf16x8, ql[cc]), acc, 0, 0, 0);
      }
      accs[tgb * 4 + t2] = acc;
    }
  }

  // ---- mask (global f16, L2-hot) + causal (global pos) + per-wave max
  const float plr = posb[l];
  const _Float16* mrow = mw + ((size_t)h * LN + l) * SN;

  float mx = -3.0e38f;
#pragma unroll
  for (int tg = 0; tg < 8; ++tg) {
    const int s0 = w * 128 + tg * 16 + cg * 4;
    f16x4 m4 = *(const f16x4*)(mrow + s0);
    float4 po4 = *(const float4*)(posb + s0);
    float pov[4] = {po4.x, po4.y, po4.z, po4.w};
#pragma unroll
    for (int r = 0; r < 4; ++r) {
      float v = fmaf(accs[tg][r], 0.125f, (float)m4[r]);
      bool maskd = (causal != 0) && (pov[r] > plr);
      v = maskd ? -1.0e30f : v;
      accs[tg][r] = v;
      mx = fmaxf(mx, v);
    }
  }
  mx = fmaxf(mx, __shfl_xor(mx, 16, 64));
  mx = fmaxf(mx, __shfl_xor(mx, 32, 64));

  // ---- per-wave exp/sum/entropy-partial (vs wave-local max)
  float zz = 0.f, ee = 0.f;
#pragma unroll
  for (int tg = 0; tg < 8; ++tg) {
#pragma unroll
    for (int r = 0; r < 4; ++r) {
      float tt = accs[tg][r] - mx;
      float ex = __expf(tt);
      zz += ex;
      ee = fmaf(ex, fmaxf(tt, -88.0f), ee);  // guard 0 * -1e30
      accs[tg][r] = ex;
    }
  }
  zz += __shfl_xor(zz, 16, 64);
  zz += __shfl_xor(zz, 32, 64);
  ee += __shfl_xor(ee, 16, 64);
  ee += __shfl_xor(ee, 32, 64);
  if (cg == 0) { redM[w][cl] = mx; redZ[w][cl] = zz; redE[w][cl] = ee; }

  __syncthreads();  // BAR 1 (softmax merge)

  // ---- online-softmax merge across the 8 waves
  float M = redM[0][cl];
#pragma unroll
  for (int i = 1; i < 8; ++i) M = fmaxf(M, redM[i][cl]);
  float Z = 0.f, E = 0.f;
#pragma unroll
  for (int i = 0; i < 8; ++i) {
    float mi = redM[i][cl];
    float sci = __expf(mi - M);
    Z += sci * redZ[i][cl];
    E = fmaf(sci, redE[i][cl] + (mi - M) * redZ[i][cl], E);
  }
  const float rz = __fdividef(1.0f, Z);
  const float scw = __expf(mx - M) * rz;  // this wave's att scale

  // ---- att: NT global fp32 store + bf16 into OWN LDS region (no barrier)
  float* ab = out + OFF_ATT + (((size_t)b * HN + h) * LN + l) * SN;
  unsigned char* wreg = lds_wav + w * WREG;
#pragma unroll
  for (int tg = 0; tg < 8; ++tg) {
    const int s0 = w * 128 + tg * 16 + cg * 4;
    float ax = accs[tg][0] * scw, ay = accs[tg][1] * scw;
    float az = accs[tg][2] * scw, aw = accs[tg][3] * scw;
    uint2v pk = uint2v{
        (__float_as_uint(ax) >> 16) | (__float_as_uint(ay) & 0xffff0000u),
        (__float_as_uint(az) >> 16) | (__float_as_uint(aw) & 0xffff0000u)};
    *(uint2v*)(wreg + cl * WPITCH + (tg * 16 + cg * 4) * 2) = pk;
    __builtin_nontemporal_store(f32x4{ax, ay, az, aw}, (f32x4*)(ab + s0));
  }
  if (w == 0 && cg == 0)
    out[OFF_ENT + ((size_t)b * HN + h) * LN + l] = __logf(Z) - E * rz;

  // ---- PV partial over own s-slice, ALL 64 e (wave-private, no barrier).
  // A = vT frag (m = e-local = cl, k = cg*8+j), B = own att (n = cl).
  const unsigned short* vbb =
      vT + ((size_t)(b * 8 + h) * 64) * 1024 + w * 128;
  f32x4 pv[4];
#pragma unroll
  for (int et = 0; et < 4; ++et) pv[et] = f32x4{0.f, 0.f, 0.f, 0.f};
#pragma unroll
  for (int kc = 0; kc < 4; ++kc) {
    uint4v af = *(const uint4v*)(wreg + cl * WPITCH + (kc * 32 + cg * 8) * 2);
    uint4v vf[4];
#pragma unroll
    for (int et = 0; et < 4; ++et)
      vf[et] = *(const uint4v*)(vbb + ((size_t)(et * 16 + cl)) * 1024 +
                                kc * 32 + cg * 8);
    bf16x8 b8 = __builtin_bit_cast(bf16x8, af);
#pragma unroll
    for (int et = 0; et < 4; ++et)
      pv[et] = __builtin_amdgcn_mfma_f32_16x16x32_bf16(
          __builtin_bit_cast(bf16x8, vf[et]), b8, pv[et], 0, 0, 0);
  }
  // D: col = cl = q-row, row = cg*4+r = e-local. Overwrite own region as
  // V-partial[l = cl][e]: f32x4 at row cl, e-offset et*16+cg*4.
#pragma unroll
  for (int et = 0; et < 4; ++et)
    *(f32x4*)(wreg + cl * WPITCH + (et * 16 + cg * 4) * 4) = pv[et];

  __syncthreads();  // BAR 2 (V partials ready)

  // ---- 8-way reduce + coalesced NT V store (512 threads: l x 32 e-pairs)
  {
    const int l_ = tid >> 5, e2 = (tid & 31) * 2;
    f32x2 s = f32x2{0.f, 0.f};
#pragma unroll
    for (int ww = 0; ww < 8; ++ww)
      s += *(const f32x2*)(lds_wav + ww * WREG + l_ * WPITCH + e2 * 4);
    float* dst = out + (((size_t)b * LN + lb * 16 + l_) * HN + h) * EN + e2;
    __builtin_nontemporal_store(s, (f32x2*)dst);
  }
}

extern "C" void kernel_launch(void* const* d_in, const int* in_sizes, int n_in,
                              void* d_out, int out_size, void* d_ws, size_t ws_size,
                              hipStream_t stream) {
  (void)in_sizes; (void)n_in; (void)out_size; (void)ws_size;
  const float* q   = (const float*)d_in[0];
  const float* k   = (const float*)d_in[1];
  const float* v   = (const float*)d_in[2];
  const float* pos = (const float*)d_in[3];
  const float* phi = (const float*)d_in[4];
  const float* u   = (const float*)d_in[5];
  const float* lt  = (const float*)d_in[6];
  const float* th  = (const float*)d_in[7];
  const int*   cm  = (const int*)d_in[8];
  float* out = (float*)d_out;

  _Float16* mw = (_Float16*)((char*)d_ws + WS_MW);
  unsigned short* kb = (unsigned short*)((char*)d_ws + WS_KB);
  unsigned short* vT = (unsigned short*)((char*)d_ws + WS_VT);

  k_prep<<<dim3(10240), dim3(256), 0, stream>>>(k, v, phi, u, lt, th, mw, kb, vT);
  k_fused<<<dim3(256, 8, 1), dim3(512), 0, stream>>>(q, kb, vT, mw, pos, cm, out);
}

// Round 14
// 124.507 us; speedup vs baseline: 1.0638x; 1.0638x over previous
//
#include <hip/hip_runtime.h>

#define BN 4
#define LN 1024
#define SN 1024
#define HN 8
#define EN 64
#define OFF_ATT (BN * LN * HN * EN)
#define OFF_ENT (OFF_ATT + BN * HN * LN * SN)

// workspace byte offsets (need ~25 MB)
#define WS_MW 0u                          // f16 mask, 8*1024*1024*2 = 16 MB
#define WS_KB 16777216u                   // bf16 K, 4 MB
#define WS_VT (WS_KB + 4194304u)          // bf16 V^T, 4 MB

// att LDS tile: 16 rows, pitch 2064 B
#define APITCH 2064

typedef __attribute__((ext_vector_type(8))) __bf16 bf16x8;
typedef __attribute__((ext_vector_type(4))) float f32x4;
typedef __attribute__((ext_vector_type(4))) unsigned int uint4v;
typedef __attribute__((ext_vector_type(2))) unsigned int uint2v;
typedef __attribute__((ext_vector_type(4))) _Float16 f16x4;

// blockIdx.x encodes (lbHi, b, lbLo): batch-siblings of an (h,l-tile) are 8
// blocks apart -> same XCD under round-robin -> shared mw slices L2-hot.
__device__ __forceinline__ void decode_block(int x, int& b, int& lb) {
  int lbLo = x & 7;
  b = (x >> 3) & 3;
  lb = (x >> 5) * 8 + lbLo;
}

// 8 consecutive floats -> packed bf16 hi + lo (trunc split)
__device__ __forceinline__ void cvt8(const float* p, uint4v& hv, uint4v& lv) {
  float4 a = *(const float4*)p;
  float4 bq = *(const float4*)(p + 4);
  float x[8] = {a.x, a.y, a.z, a.w, bq.x, bq.y, bq.z, bq.w};
  unsigned int h[8], lo[8];
#pragma unroll
  for (int i = 0; i < 8; ++i) {
    unsigned int ub = __float_as_uint(x[i]);
    h[i] = ub >> 16;
    float lf = x[i] - __uint_as_float(ub & 0xffff0000u);
    lo[i] = __float_as_uint(lf) >> 16;
  }
  hv = uint4v{h[0] | (h[1] << 16), h[2] | (h[3] << 16),
              h[4] | (h[5] << 16), h[6] | (h[7] << 16)};
  lv = uint4v{lo[0] | (lo[1] << 16), lo[2] | (lo[3] << 16),
              lo[4] | (lo[5] << 16), lo[6] | (lo[7] << 16)};
}

__device__ __forceinline__ uint4v pack8_trunc(float4 a, float4 b) {
  return uint4v{(__float_as_uint(a.x) >> 16) | (__float_as_uint(a.y) & 0xffff0000u),
                (__float_as_uint(a.z) >> 16) | (__float_as_uint(a.w) & 0xffff0000u),
                (__float_as_uint(b.x) >> 16) | (__float_as_uint(b.y) & 0xffff0000u),
                (__float_as_uint(b.z) >> 16) | (__float_as_uint(b.w) & 0xffff0000u)};
}

// ---------------- fused prep kernel (mask + K + V^T) ----------------
// blocks [0,8192): phi-mask f16; [8192,9216): K->bf16; [9216,10240): V->vT.
__global__ __launch_bounds__(256) void k_prep(
    const float* __restrict__ kk, const float* __restrict__ vv,
    const float* __restrict__ phi, const float* __restrict__ u,
    const float* __restrict__ p_logtau, const float* __restrict__ p_thresh,
    _Float16* __restrict__ mw, unsigned short* __restrict__ kb,
    unsigned short* __restrict__ vT) {
  const int bx = blockIdx.x;
  if (bx < 8192) {
    const float tau = fminf(fmaxf(__expf(p_logtau[0]), 0.1f), 5.0f);
    const float rtau = 1.0f / tau;
    const float thr = fminf(fmaxf(p_thresh[0], 0.01f), 0.99f);
    int idx = (bx * 256 + threadIdx.x) * 4;
    float4 u4 = *(const float4*)(u + idx);
    float4 p4 = *(const float4*)(phi + idx);
    float uu[4] = {u4.x, u4.y, u4.z, u4.w};
    float pp[4] = {p4.x, p4.y, p4.z, p4.w};
    f16x4 o;
#pragma unroll
    for (int i = 0; i < 4; ++i) {
      float g = __logf(__fdividef(uu[i] + 1e-8f, 1.0f - uu[i] + 1e-8f));
      float z = (g + pp[i]) * rtau;
      float sig = __fdividef(1.0f, 1.0f + __expf(-z));
      o[i] = (_Float16)(-10000.0f * fmaxf(thr - sig, 0.0f) * 0.125f);
    }
    *(f16x4*)(mw + idx) = o;
  } else if (bx < 9216) {
    int gid = (bx - 8192) * 256 + threadIdx.x;
    int e8 = gid & 7;
    int tmp = gid >> 3;
    int h = tmp & 7;
    int bs = tmp >> 3;
    int s = bs & 1023;
    int b = bs >> 10;
    const float* src = kk + (size_t)gid * 8;
    float4 a = *(const float4*)src;
    float4 bq = *(const float4*)(src + 4);
    *(uint4v*)(kb + (((size_t)(b * 8 + h) * 1024 + s) * 64) + e8 * 8) =
        pack8_trunc(a, bq);
  } else {
    int gid = (bx - 9216) * 256 + threadIdx.x;
    int s8 = gid & 127;
    int t1 = gid >> 7;
    int e = t1 & 63;
    int t2 = t1 >> 6;
    int h = t2 & 7;
    int b = t2 >> 3;
    float x[8];
#pragma unroll
    for (int j = 0; j < 8; ++j)
      x[j] = vv[((size_t)(b * 1024 + s8 * 8 + j) * 8 + h) * 64 + e];
    uint4v pv = pack8_trunc(float4{x[0], x[1], x[2], x[3]},
                            float4{x[4], x[5], x[6], x[7]});
    *(uint4v*)(vT + ((size_t)(b * 8 + h) * 64 + e) * 1024 + s8 * 8) = pv;
  }
}

// ---------------- fused scores + mask + softmax + entropy + PV ----------------
// Block = 8 waves (512 thr), 16 q-rows of one (b,h). R11 structure with:
// (a) causal via integer compare s > l (pos is arange -> exact), no pos
//     loads, no staging barrier (4 barriers total);
// (b) all 8 mask loads issued at kernel top, consumed after QK (~2000 cyc
//     later) -> latency fully hidden; register budget raised to the 128-reg
//     bucket ceiling (launch_bounds(512,4), same 16 waves/CU as R11).
// All output stores after the last barrier; PV partials in dedicated LDS.
__global__ __launch_bounds__(512, 4) void k_fused(
    const float* __restrict__ q, const unsigned short* __restrict__ kb,
    const unsigned short* __restrict__ vT, const _Float16* __restrict__ mw,
    const int* __restrict__ p_causal, float* __restrict__ out) {
  int b, lb;
  decode_block(blockIdx.x, b, lb);
  const int h = blockIdx.y;
  const int tid = threadIdx.x;
  const int w = __builtin_amdgcn_readfirstlane(tid >> 6);  // 0..7
  const int c = tid & 63;
  const int cl = c & 15;
  const int cg = c >> 4;

  __shared__ __align__(16) unsigned char lds_att[16 * APITCH];
  __shared__ __align__(16) unsigned char lds_part[8192];
  __shared__ float red0[8][16], redZ[8][16], redE[8][16];

  const int causal = p_causal[0];
  const int l = lb * 16 + cl;  // this lane's q-row
  const unsigned short* kbb = kb + ((size_t)(b * 8 + h) * 1024) * 64;

  // ---- issue ALL mask loads first (consumed after QK; latency hidden)
  const _Float16* mrow = mw + ((size_t)h * LN + l) * SN;
  f16x4 mk8[8];
#pragma unroll
  for (int tg = 0; tg < 8; ++tg)
    mk8[tg] = *(const f16x4*)(mrow + w * 128 + tg * 16 + cg * 4);

  // ---- Q fragments (B operand): n = cl (q-row), k = cg*8+j
  uint4v qh[2], ql[2];
#pragma unroll
  for (int cc = 0; cc < 2; ++cc) {
    const float* qp = q + (((size_t)b * LN + l) * HN + h) * EN + cc * 32 + cg * 8;
    cvt8(qp, qh[cc], ql[cc]);
  }

  f32x4 accs[8];

  // ---- QK^T: 2 batches of 4 tiles (8 loads in flight, then 16 MFMAs)
#pragma unroll
  for (int tgb = 0; tgb < 2; ++tgb) {
    uint4v kf[4][2];
#pragma unroll
    for (int t2 = 0; t2 < 4; ++t2)
#pragma unroll
      for (int cc = 0; cc < 2; ++cc)
        kf[t2][cc] = *(const uint4v*)(kbb +
                                      (size_t)(w * 128 + (tgb * 4 + t2) * 16 + cl) * 64 +
                                      cc * 32 + cg * 8);
#pragma unroll
    for (int t2 = 0; t2 < 4; ++t2) {
      f32x4 acc = f32x4{0.f, 0.f, 0.f, 0.f};
#pragma unroll
      for (int cc = 0; cc < 2; ++cc) {
        bf16x8 kv = __builtin_bit_cast(bf16x8, kf[t2][cc]);
        acc = __builtin_amdgcn_mfma_f32_16x16x32_bf16(
            kv, __builtin_bit_cast(bf16x8, qh[cc]), acc, 0, 0, 0);
        acc = __builtin_amdgcn_mfma_f32_16x16x32_bf16(
            kv, __builtin_bit_cast(bf16x8, ql[cc]), acc, 0, 0, 0);
      }
      accs[tgb * 4 + t2] = acc;
    }
  }

  // ---- mask (regs, already landed) + integer causal (s > l) + max
  float mx = -3.0e38f;
#pragma unroll
  for (int tg = 0; tg < 8; ++tg) {
    const int s0 = w * 128 + tg * 16 + cg * 4;
#pragma unroll
    for (int r = 0; r < 4; ++r) {
      float v = fmaf(accs[tg][r], 0.125f, (float)mk8[tg][r]);
      bool maskd = (causal != 0) && (s0 + r > l);
      v = maskd ? -1.0e30f : v;
      accs[tg][r] = v;
      mx = fmaxf(mx, v);
    }
  }
  mx = fmaxf(mx, __shfl_xor(mx, 16, 64));
  mx = fmaxf(mx, __shfl_xor(mx, 32, 64));
  if (cg == 0) red0[w][cl] = mx;
  __syncthreads();  // bar1
  float bmx = red0[0][cl];
#pragma unroll
  for (int i = 1; i < 8; ++i) bmx = fmaxf(bmx, red0[i][cl]);

  float zz = 0.f, ee = 0.f;
#pragma unroll
  for (int tg = 0; tg < 8; ++tg) {
#pragma unroll
    for (int r = 0; r < 4; ++r) {
      float tt = accs[tg][r] - bmx;
      float ex = __expf(tt);
      zz += ex;
      ee = fmaf(ex, fmaxf(tt, -88.0f), ee);  // guard 0 * -1e30
      accs[tg][r] = ex;
    }
  }
  zz += __shfl_xor(zz, 16, 64);
  zz += __shfl_xor(zz, 32, 64);
  ee += __shfl_xor(ee, 16, 64);
  ee += __shfl_xor(ee, 32, 64);
  if (cg == 0) { redZ[w][cl] = zz; redE[w][cl] = ee; }

  // ---- vT batch-0 prefetch (independent of LDS; hides under bar2/bar3)
  const int et = w & 3, sh = w >> 2;
  const unsigned short* vbb =
      vT + ((size_t)(b * 8 + h) * 64 + et * 16 + cl) * 1024 + sh * 512;
  uint4v vf0[8];
#pragma unroll
  for (int j = 0; j < 8; ++j)
    vf0[j] = *(const uint4v*)(vbb + j * 32 + cg * 8);

  __syncthreads();  // bar2
  float Z = redZ[0][cl], E = redE[0][cl];
#pragma unroll
  for (int i = 1; i < 8; ++i) { Z += redZ[i][cl]; E += redE[i][cl]; }
  const float rz = __fdividef(1.0f, Z);
  const float entv = __logf(Z) - E * rz;

  // ---- normalized bf16 att into LDS
  unsigned char* arow = lds_att + cl * APITCH;
#pragma unroll
  for (int tg = 0; tg < 8; ++tg) {
    const int s0 = w * 128 + tg * 16 + cg * 4;
    float ax = accs[tg][0] * rz, ay = accs[tg][1] * rz;
    float az = accs[tg][2] * rz, aw = accs[tg][3] * rz;
    uint2v pk = uint2v{
        (__float_as_uint(ax) >> 16) | (__float_as_uint(ay) & 0xffff0000u),
        (__float_as_uint(az) >> 16) | (__float_as_uint(aw) & 0xffff0000u)};
    *(uint2v*)(arow + s0 * 2) = pk;
  }

  __syncthreads();  // bar3: full att tile visible

  // ---- PV: wave w -> e-tile et, s-half sh. Batch 0 uses prefetched vf0.
  f32x4 acc0 = f32x4{0.f, 0.f, 0.f, 0.f};
  f32x4 acc1 = f32x4{0.f, 0.f, 0.f, 0.f};
  {
    uint4v af[8];
#pragma unroll
    for (int j = 0; j < 8; ++j)
      af[j] = *(const uint4v*)(lds_att + cl * APITCH +
                               (sh * 512 + j * 32 + cg * 8) * 2);
#pragma unroll
    for (int j = 0; j < 8; ++j) {
      bf16x8 a8 = __builtin_bit_cast(bf16x8, vf0[j]);
      bf16x8 b8 = __builtin_bit_cast(bf16x8, af[j]);
      if (j & 1)
        acc1 = __builtin_amdgcn_mfma_f32_16x16x32_bf16(a8, b8, acc1, 0, 0, 0);
      else
        acc0 = __builtin_amdgcn_mfma_f32_16x16x32_bf16(a8, b8, acc0, 0, 0, 0);
    }
  }
  {
    uint4v vf[8], af[8];
#pragma unroll
    for (int j = 0; j < 8; ++j) {
      const int sc = 8 + j;
      vf[j] = *(const uint4v*)(vbb + sc * 32 + cg * 8);
      af[j] = *(const uint4v*)(lds_att + cl * APITCH +
                               (sh * 512 + sc * 32 + cg * 8) * 2);
    }
#pragma unroll
    for (int j = 0; j < 8; ++j) {
      bf16x8 a8 = __builtin_bit_cast(bf16x8, vf[j]);
      bf16x8 b8 = __builtin_bit_cast(bf16x8, af[j]);
      if (j & 1)
        acc1 = __builtin_amdgcn_mfma_f32_16x16x32_bf16(a8, b8, acc1, 0, 0, 0);
      else
        acc0 = __builtin_amdgcn_mfma_f32_16x16x32_bf16(a8, b8, acc0, 0, 0, 0);
    }
  }
  f32x4 sum = acc0 + acc1;

  // partials to dedicated LDS (att tile stays intact for the final write)
  *(f32x4*)(lds_part + w * 1024 + cl * 64 + cg * 16) = sum;

  __syncthreads();  // bar4: LAST barrier — no output store issued yet

  // ---- all global output stores issued after the last barrier ----
  // V: cross s-half reduce + coalesced NT store
  if (tid < 256) {
    const int l_ = tid >> 4, e4 = tid & 15, et_ = e4 >> 2;
    f32x4 p0 = *(const f32x4*)(lds_part + et_ * 1024 + l_ * 64 + (e4 & 3) * 16);
    f32x4 p1 = *(const f32x4*)(lds_part + (et_ + 4) * 1024 + l_ * 64 + (e4 & 3) * 16);
    f32x4 s = p0 + p1;
    float* dst = out + (((size_t)b * LN + lb * 16 + l_) * HN + h) * EN + e4 * 4;
    __builtin_nontemporal_store(s, (f32x4*)dst);
  }
  // entropy
  if (w == 0 && cg == 0)
    out[OFF_ENT + ((size_t)b * HN + h) * LN + l] = entv;
  // att fp32: wave w -> rows w*2, w*2+1 (LDS tile intact)
  {
    float* abase = out + OFF_ATT + (((size_t)b * HN + h) * LN + lb * 16) * SN;
#pragma unroll
    for (int rr = 0; rr < 2; ++rr) {
      const int row = w * 2 + rr;
      const unsigned char* src = lds_att + row * APITCH;
      float* dst = abase + (size_t)row * SN;
#pragma unroll
      for (int it = 0; it < 4; ++it) {
        uint2v pk = *(const uint2v*)(src + it * 512 + c * 8);
        f32x4 o = f32x4{__uint_as_float(pk.x << 16),
                        __uint_as_float(pk.x & 0xffff0000u),
                        __uint_as_float(pk.y << 16),
                        __uint_as_float(pk.y & 0xffff0000u)};
        __builtin_nontemporal_store(o, (f32x4*)(dst + it * 256 + c * 4));
      }
    }
  }
}

extern "C" void kernel_launch(void* const* d_in, const int* in_sizes, int n_in,
                              void* d_out, int out_size, void* d_ws, size_t ws_size,
                              hipStream_t stream) {
  (void)in_sizes; (void)n_in; (void)out_size; (void)ws_size;
  const float* q   = (const float*)d_in[0];
  const float* k   = (const float*)d_in[1];
  const float* v   = (const float*)d_in[2];
  const float* phi = (const float*)d_in[4];
  const float* u   = (const float*)d_in[5];
  const float* lt  = (const float*)d_in[6];
  const float* th  = (const float*)d_in[7];
  const int*   cm  = (const int*)d_in[8];
  float* out = (float*)d_out;

  _Float16* mw = (_Float16*)((char*)d_ws + WS_MW);
  unsigned short* kb = (unsigned short*)((char*)d_ws + WS_KB);
  unsigned short* vT = (unsigned short*)((char*)d_ws + WS_VT);

  k_prep<<<dim3(10240), dim3(256), 0, stream>>>(k, v, phi, u, lt, th, mw, kb, vT);
  k_fused<<<dim3(256, 8, 1), dim3(512), 0, stream>>>(q, kb, vT, mw, cm, out);
}

// Round 15
// 104.193 us; speedup vs baseline: 1.2713x; 1.1950x over previous
//
#include <hip/hip_runtime.h>

#define BN 4
#define LN 1024
#define SN 1024
#define HN 8
#define EN 64
#define OFF_ATT (BN * LN * HN * EN)
#define OFF_ENT (OFF_ATT + BN * HN * LN * SN)

// workspace byte offsets (need ~25 MB)
#define WS_MW 0u                          // f16 mask, 8*1024*1024*2 = 16 MB
#define WS_KB 16777216u                   // bf16 K, 4 MB
#define WS_VT (WS_KB + 4194304u)          // bf16 V^T, 4 MB

// att/mask LDS tile: 32 rows, pitch 2064 B (516 dwords == 4 mod 32 banks)
#define APITCH 2064

typedef __attribute__((ext_vector_type(8))) __bf16 bf16x8;
typedef __attribute__((ext_vector_type(4))) float f32x4;
typedef __attribute__((ext_vector_type(4))) unsigned int uint4v;
typedef __attribute__((ext_vector_type(2))) unsigned int uint2v;
typedef __attribute__((ext_vector_type(4))) _Float16 f16x4;

// blockIdx.x (0..127) encodes (lbHi, b, lbLo): batch-siblings of an
// (h,l-tile) are 8 blocks apart -> same XCD -> mw slices L2-hot.
__device__ __forceinline__ void decode_block(int x, int& b, int& lb) {
  int lbLo = x & 7;
  b = (x >> 3) & 3;
  lb = (x >> 5) * 8 + lbLo;  // 0..31 (32-row tiles)
}

// 8 consecutive floats -> packed bf16 hi + lo (trunc split)
__device__ __forceinline__ void cvt8(const float* p, uint4v& hv, uint4v& lv) {
  float4 a = *(const float4*)p;
  float4 bq = *(const float4*)(p + 4);
  float x[8] = {a.x, a.y, a.z, a.w, bq.x, bq.y, bq.z, bq.w};
  unsigned int h[8], lo[8];
#pragma unroll
  for (int i = 0; i < 8; ++i) {
    unsigned int ub = __float_as_uint(x[i]);
    h[i] = ub >> 16;
    float lf = x[i] - __uint_as_float(ub & 0xffff0000u);
    lo[i] = __float_as_uint(lf) >> 16;
  }
  hv = uint4v{h[0] | (h[1] << 16), h[2] | (h[3] << 16),
              h[4] | (h[5] << 16), h[6] | (h[7] << 16)};
  lv = uint4v{lo[0] | (lo[1] << 16), lo[2] | (lo[3] << 16),
              lo[4] | (lo[5] << 16), lo[6] | (lo[7] << 16)};
}

__device__ __forceinline__ uint4v pack8_trunc(float4 a, float4 b) {
  return uint4v{(__float_as_uint(a.x) >> 16) | (__float_as_uint(a.y) & 0xffff0000u),
                (__float_as_uint(a.z) >> 16) | (__float_as_uint(a.w) & 0xffff0000u),
                (__float_as_uint(b.x) >> 16) | (__float_as_uint(b.y) & 0xffff0000u),
                (__float_as_uint(b.z) >> 16) | (__float_as_uint(b.w) & 0xffff0000u)};
}

// ---------------- fused prep kernel (mask + K + V^T) ----------------
__global__ __launch_bounds__(256) void k_prep(
    const float* __restrict__ kk, const float* __restrict__ vv,
    const float* __restrict__ phi, const float* __restrict__ u,
    const float* __restrict__ p_logtau, const float* __restrict__ p_thresh,
    _Float16* __restrict__ mw, unsigned short* __restrict__ kb,
    unsigned short* __restrict__ vT) {
  const int bx = blockIdx.x;
  if (bx < 8192) {
    const float tau = fminf(fmaxf(__expf(p_logtau[0]), 0.1f), 5.0f);
    const float rtau = 1.0f / tau;
    const float thr = fminf(fmaxf(p_thresh[0], 0.01f), 0.99f);
    int idx = (bx * 256 + threadIdx.x) * 4;
    float4 u4 = *(const float4*)(u + idx);
    float4 p4 = *(const float4*)(phi + idx);
    float uu[4] = {u4.x, u4.y, u4.z, u4.w};
    float pp[4] = {p4.x, p4.y, p4.z, p4.w};
    f16x4 o;
#pragma unroll
    for (int i = 0; i < 4; ++i) {
      float g = __logf(__fdividef(uu[i] + 1e-8f, 1.0f - uu[i] + 1e-8f));
      float z = (g + pp[i]) * rtau;
      float sig = __fdividef(1.0f, 1.0f + __expf(-z));
      o[i] = (_Float16)(-10000.0f * fmaxf(thr - sig, 0.0f) * 0.125f);
    }
    *(f16x4*)(mw + idx) = o;
  } else if (bx < 9216) {
    int gid = (bx - 8192) * 256 + threadIdx.x;
    int e8 = gid & 7;
    int tmp = gid >> 3;
    int h = tmp & 7;
    int bs = tmp >> 3;
    int s = bs & 1023;
    int b = bs >> 10;
    const float* src = kk + (size_t)gid * 8;
    float4 a = *(const float4*)src;
    float4 bq = *(const float4*)(src + 4);
    *(uint4v*)(kb + (((size_t)(b * 8 + h) * 1024 + s) * 64) + e8 * 8) =
        pack8_trunc(a, bq);
  } else {
    int gid = (bx - 9216) * 256 + threadIdx.x;
    int s8 = gid & 127;
    int t1 = gid >> 7;
    int e = t1 & 63;
    int t2 = t1 >> 6;
    int h = t2 & 7;
    int b = t2 >> 3;
    float x[8];
#pragma unroll
    for (int j = 0; j < 8; ++j)
      x[j] = vv[((size_t)(b * 1024 + s8 * 8 + j) * 8 + h) * 64 + e];
    uint4v pv = pack8_trunc(float4{x[0], x[1], x[2], x[3]},
                            float4{x[4], x[5], x[6], x[7]});
    *(uint4v*)(vT + ((size_t)(b * 8 + h) * 64 + e) * 1024 + s8 * 8) = pv;
  }
}

// ---------------- fused: 32 q-rows/block, 2 sequential 16-row passes ----
// 8 waves (512 thr). Wave w owns s-range [w*128, w*128+128). Per q-tile qt:
// swapped QK^T (accs[8] reused across qt -> AGPR flat), LDS f16 mask
// (staged coalesced; row qt*16+cl, per-wave byte range disjoint), integer
// causal, block softmax, att bf16 into same LDS row. Then: att fp32 write
// (coalesced from LDS) + PV where each vT fragment is loaded ONCE and used
// for BOTH q-tiles (vT L2 traffic halved per row). Partials reuse the att
// region post-barrier -> LDS 69KB, 2 blocks/CU.
__global__ __launch_bounds__(512, 4) void k_fused(
    const float* __restrict__ q, const unsigned short* __restrict__ kb,
    const unsigned short* __restrict__ vT, const _Float16* __restrict__ mw,
    const int* __restrict__ p_causal, float* __restrict__ out) {
  int b, lb;
  decode_block(blockIdx.x, b, lb);
  const int h = blockIdx.y;
  const int tid = threadIdx.x;
  const int w = __builtin_amdgcn_readfirstlane(tid >> 6);  // 0..7
  const int c = tid & 63;
  const int cl = c & 15;
  const int cg = c >> 4;

  __shared__ __align__(16) unsigned char lds_att[32 * APITCH];  // 66 KB
  __shared__ float red0[8][16], redZ[8][16], redE[8][16];

  const int causal = p_causal[0];
  const unsigned short* kbb = kb + ((size_t)(b * 8 + h) * 1024) * 64;

  // ---- phase 0: stage 32 mask rows (64 KB) coalesced into LDS
  {
    const unsigned char* gmask =
        (const unsigned char*)(mw + ((size_t)h * LN + lb * 32) * SN);
    uint4v mk[8];
#pragma unroll
    for (int i = 0; i < 8; ++i)
      mk[i] = *(const uint4v*)(gmask + i * 8192 + tid * 16);
#pragma unroll
    for (int i = 0; i < 8; ++i) {
      int goff = i * 8192 + tid * 16;
      *(uint4v*)(lds_att + (goff >> 11) * APITCH + (goff & 2047)) = mk[i];
    }
  }
  __syncthreads();  // bar: mask staged

  // ---- two sequential 16-row q-tile passes
#pragma unroll
  for (int qt = 0; qt < 2; ++qt) {
    const int l = lb * 32 + qt * 16 + cl;  // this lane's q-row

    uint4v qh[2], ql[2];
#pragma unroll
    for (int cc = 0; cc < 2; ++cc) {
      const float* qp = q + (((size_t)b * LN + l) * HN + h) * EN + cc * 32 + cg * 8;
      cvt8(qp, qh[cc], ql[cc]);
    }

    f32x4 accs[8];
#pragma unroll
    for (int tgb = 0; tgb < 2; ++tgb) {
      uint4v kf[4][2];
#pragma unroll
      for (int t2 = 0; t2 < 4; ++t2)
#pragma unroll
        for (int cc = 0; cc < 2; ++cc)
          kf[t2][cc] = *(const uint4v*)(kbb +
                                        (size_t)(w * 128 + (tgb * 4 + t2) * 16 + cl) * 64 +
                                        cc * 32 + cg * 8);
#pragma unroll
      for (int t2 = 0; t2 < 4; ++t2) {
        f32x4 acc = f32x4{0.f, 0.f, 0.f, 0.f};
#pragma unroll
        for (int cc = 0; cc < 2; ++cc) {
          bf16x8 kv = __builtin_bit_cast(bf16x8, kf[t2][cc]);
          acc = __builtin_amdgcn_mfma_f32_16x16x32_bf16(
              kv, __builtin_bit_cast(bf16x8, qh[cc]), acc, 0, 0, 0);
          acc = __builtin_amdgcn_mfma_f32_16x16x32_bf16(
              kv, __builtin_bit_cast(bf16x8, ql[cc]), acc, 0, 0, 0);
        }
        accs[tgb * 4 + t2] = acc;
      }
    }

    // mask (LDS row qt*16+cl, own s-range bytes) + integer causal + max
    const unsigned char* mrow = lds_att + (qt * 16 + cl) * APITCH;
    float mx = -3.0e38f;
#pragma unroll
    for (int tg = 0; tg < 8; ++tg) {
      const int s0 = w * 128 + tg * 16 + cg * 4;
      f16x4 m4 = *(const f16x4*)(mrow + s0 * 2);
#pragma unroll
      for (int r = 0; r < 4; ++r) {
        float v = fmaf(accs[tg][r], 0.125f, (float)m4[r]);
        bool maskd = (causal != 0) && (s0 + r > l);
        v = maskd ? -1.0e30f : v;
        accs[tg][r] = v;
        mx = fmaxf(mx, v);
      }
    }
    mx = fmaxf(mx, __shfl_xor(mx, 16, 64));
    mx = fmaxf(mx, __shfl_xor(mx, 32, 64));
    if (cg == 0) red0[w][cl] = mx;
    __syncthreads();
    float bmx = red0[0][cl];
#pragma unroll
    for (int i = 1; i < 8; ++i) bmx = fmaxf(bmx, red0[i][cl]);

    float zz = 0.f, ee = 0.f;
#pragma unroll
    for (int tg = 0; tg < 8; ++tg) {
#pragma unroll
      for (int r = 0; r < 4; ++r) {
        float tt = accs[tg][r] - bmx;
        float ex = __expf(tt);
        zz += ex;
        ee = fmaf(ex, fmaxf(tt, -88.0f), ee);  // guard 0 * -1e30
        accs[tg][r] = ex;
      }
    }
    zz += __shfl_xor(zz, 16, 64);
    zz += __shfl_xor(zz, 32, 64);
    ee += __shfl_xor(ee, 16, 64);
    ee += __shfl_xor(ee, 32, 64);
    if (cg == 0) { redZ[w][cl] = zz; redE[w][cl] = ee; }
    __syncthreads();
    float Z = redZ[0][cl], E = redE[0][cl];
#pragma unroll
    for (int i = 1; i < 8; ++i) { Z += redZ[i][cl]; E += redE[i][cl]; }
    const float rz = __fdividef(1.0f, Z);
    if (w == 0 && cg == 0)
      out[OFF_ENT + ((size_t)b * HN + h) * LN + l] = __logf(Z) - E * rz;

    // normalized bf16 att into LDS (own row, own s-range — no hazard)
    unsigned char* arow = lds_att + (qt * 16 + cl) * APITCH;
#pragma unroll
    for (int tg = 0; tg < 8; ++tg) {
      const int s0 = w * 128 + tg * 16 + cg * 4;
      float ax = accs[tg][0] * rz, ay = accs[tg][1] * rz;
      float az = accs[tg][2] * rz, aw = accs[tg][3] * rz;
      uint2v pk = uint2v{
          (__float_as_uint(ax) >> 16) | (__float_as_uint(ay) & 0xffff0000u),
          (__float_as_uint(az) >> 16) | (__float_as_uint(aw) & 0xffff0000u)};
      *(uint2v*)(arow + s0 * 2) = pk;
    }
  }

  // ---- vT batch-0 prefetch (independent of LDS)
  const int et = w & 3, sh = w >> 2;
  const unsigned short* vbb =
      vT + ((size_t)(b * 8 + h) * 64 + et * 16 + cl) * 1024 + sh * 512;
  uint4v vf0[8];
#pragma unroll
  for (int j = 0; j < 8; ++j)
    vf0[j] = *(const uint4v*)(vbb + j * 32 + cg * 8);

  __syncthreads();  // bar: full 32-row att tile visible

  // ---- coalesced NT fp32 att write: wave w -> rows w*4..w*4+3
  {
    float* abase = out + OFF_ATT + (((size_t)b * HN + h) * LN + lb * 32) * SN;
#pragma unroll
    for (int rr = 0; rr < 4; ++rr) {
      const int row = w * 4 + rr;
      const unsigned char* src = lds_att + row * APITCH;
      float* dst = abase + (size_t)row * SN;
#pragma unroll
      for (int it = 0; it < 4; ++it) {
        uint2v pk = *(const uint2v*)(src + it * 512 + c * 8);
        f32x4 o = f32x4{__uint_as_float(pk.x << 16),
                        __uint_as_float(pk.x & 0xffff0000u),
                        __uint_as_float(pk.y << 16),
                        __uint_as_float(pk.y & 0xffff0000u)};
        __builtin_nontemporal_store(o, (f32x4*)(dst + it * 256 + c * 4));
      }
    }
  }

  // ---- PV: wave w -> (e-tile et, s-half sh); each vT fragment used for
  // BOTH q-tiles. acc[qt] pairs; 32 MFMAs/wave.
  f32x4 acc00 = f32x4{0.f, 0.f, 0.f, 0.f}, acc01 = f32x4{0.f, 0.f, 0.f, 0.f};
  f32x4 acc10 = f32x4{0.f, 0.f, 0.f, 0.f}, acc11 = f32x4{0.f, 0.f, 0.f, 0.f};
#pragma unroll
  for (int scb = 0; scb < 2; ++scb) {
    uint4v vf[8];
    if (scb == 0) {
#pragma unroll
      for (int j = 0; j < 8; ++j) vf[j] = vf0[j];
    } else {
#pragma unroll
      for (int j = 0; j < 8; ++j)
        vf[j] = *(const uint4v*)(vbb + 256 + j * 32 + cg * 8);
    }
#pragma unroll
    for (int qt = 0; qt < 2; ++qt) {
      uint4v af[8];
#pragma unroll
      for (int j = 0; j < 8; ++j)
        af[j] = *(const uint4v*)(lds_att + (qt * 16 + cl) * APITCH +
                                 (sh * 512 + scb * 256 + j * 32 + cg * 8) * 2);
#pragma unroll
      for (int j = 0; j < 8; ++j) {
        bf16x8 a8 = __builtin_bit_cast(bf16x8, vf[j]);
        bf16x8 b8 = __builtin_bit_cast(bf16x8, af[j]);
        if (qt == 0) {
          if (j & 1)
            acc01 = __builtin_amdgcn_mfma_f32_16x16x32_bf16(a8, b8, acc01, 0, 0, 0);
          else
            acc00 = __builtin_amdgcn_mfma_f32_16x16x32_bf16(a8, b8, acc00, 0, 0, 0);
        } else {
          if (j & 1)
            acc11 = __builtin_amdgcn_mfma_f32_16x16x32_bf16(a8, b8, acc11, 0, 0, 0);
          else
            acc10 = __builtin_amdgcn_mfma_f32_16x16x32_bf16(a8, b8, acc10, 0, 0, 0);
        }
      }
    }
  }
  f32x4 sum0 = acc00 + acc01;
  f32x4 sum1 = acc10 + acc11;

  __syncthreads();  // bar: all PV att reads done — att region now reusable

  // partials into reused att region: row qt*16+cl, byte sh*1024 + e_local*4
  *(f32x4*)(lds_att + cl * APITCH + sh * 1024 + (et * 16 + cg * 4) * 4) = sum0;
  *(f32x4*)(lds_att + (16 + cl) * APITCH + sh * 1024 + (et * 16 + cg * 4) * 4) = sum1;

  __syncthreads();  // bar: partials ready

  // ---- V: 2-way s-half reduce + coalesced NT store (512 thr = 32 r x 16 e4)
  {
    const int r = tid >> 4, e4 = tid & 15;
    f32x4 p0 = *(const f32x4*)(lds_att + r * APITCH + e4 * 16);
    f32x4 p1 = *(const f32x4*)(lds_att + r * APITCH + 1024 + e4 * 16);
    f32x4 s = p0 + p1;
    float* dst = out + (((size_t)b * LN + lb * 32 + r) * HN + h) * EN + e4 * 4;
    __builtin_nontemporal_store(s, (f32x4*)dst);
  }
}

extern "C" void kernel_launch(void* const* d_in, const int* in_sizes, int n_in,
                              void* d_out, int out_size, void* d_ws, size_t ws_size,
                              hipStream_t stream) {
  (void)in_sizes; (void)n_in; (void)out_size; (void)ws_size;
  const float* q   = (const float*)d_in[0];
  const float* k   = (const float*)d_in[1];
  const float* v   = (const float*)d_in[2];
  const float* phi = (const float*)d_in[4];
  const float* u   = (const float*)d_in[5];
  const float* lt  = (const float*)d_in[6];
  const float* th  = (const float*)d_in[7];
  const int*   cm  = (const int*)d_in[8];
  float* out = (float*)d_out;

  _Float16* mw = (_Float16*)((char*)d_ws + WS_MW);
  unsigned short* kb = (unsigned short*)((char*)d_ws + WS_KB);
  unsigned short* vT = (unsigned short*)((char*)d_ws + WS_VT);

  k_prep<<<dim3(10240), dim3(256), 0, stream>>>(k, v, phi, u, lt, th, mw, kb, vT);
  k_fused<<<dim3(128, 8, 1), dim3(512), 0, stream>>>(q, kb, vT, mw, cm, out);
}

// Round 16
// 91.783 us; speedup vs baseline: 1.4432x; 1.1352x over previous
//
#include <hip/hip_runtime.h>

#define BN 4
#define LN 1024
#define SN 1024
#define HN 8
#define EN 64
#define OFF_ATT (BN * LN * HN * EN)
#define OFF_ENT (OFF_ATT + BN * HN * LN * SN)

// workspace byte offsets (need ~25 MB)
#define WS_MW 0u                          // f16 mask, 8*1024*1024*2 = 16 MB
#define WS_KB 16777216u                   // bf16 K, 4 MB
#define WS_VT (WS_KB + 4194304u)          // bf16 V^T, 4 MB

// att/mask LDS tile: 32 rows, pitch 2064 B (516 dwords == 4 mod 32 banks)
#define APITCH 2064

typedef __attribute__((ext_vector_type(8))) __bf16 bf16x8;
typedef __attribute__((ext_vector_type(4))) float f32x4;
typedef __attribute__((ext_vector_type(4))) unsigned int uint4v;
typedef __attribute__((ext_vector_type(2))) unsigned int uint2v;
typedef __attribute__((ext_vector_type(4))) _Float16 f16x4;

// blockIdx.x (0..127) encodes (lbHi, b, lbLo): batch-siblings of an
// (h,l-tile) are 8 blocks apart -> same XCD -> mw slices L2-hot.
__device__ __forceinline__ void decode_block(int x, int& b, int& lb) {
  int lbLo = x & 7;
  b = (x >> 3) & 3;
  lb = (x >> 5) * 8 + lbLo;  // 0..31 (32-row tiles)
}

// round-to-nearest-even fp32 -> bf16 pair, packed (lo in low half)
__device__ __forceinline__ unsigned int rne2(float x, float y) {
  unsigned int ux = __float_as_uint(x), uy = __float_as_uint(y);
  ux += 0x7fffu + ((ux >> 16) & 1u);
  uy += 0x7fffu + ((uy >> 16) & 1u);
  return (ux >> 16) | (uy & 0xffff0000u);
}

__device__ __forceinline__ uint4v pack8_rne(float4 a, float4 b) {
  return uint4v{rne2(a.x, a.y), rne2(a.z, a.w), rne2(b.x, b.y), rne2(b.z, b.w)};
}

// ---------------- fused prep kernel (mask + K + V^T) ----------------
__global__ __launch_bounds__(256) void k_prep(
    const float* __restrict__ kk, const float* __restrict__ vv,
    const float* __restrict__ phi, const float* __restrict__ u,
    const float* __restrict__ p_logtau, const float* __restrict__ p_thresh,
    _Float16* __restrict__ mw, unsigned short* __restrict__ kb,
    unsigned short* __restrict__ vT) {
  const int bx = blockIdx.x;
  if (bx < 8192) {
    const float tau = fminf(fmaxf(__expf(p_logtau[0]), 0.1f), 5.0f);
    const float rtau = 1.0f / tau;
    const float thr = fminf(fmaxf(p_thresh[0], 0.01f), 0.99f);
    int idx = (bx * 256 + threadIdx.x) * 4;
    float4 u4 = *(const float4*)(u + idx);
    float4 p4 = *(const float4*)(phi + idx);
    float uu[4] = {u4.x, u4.y, u4.z, u4.w};
    float pp[4] = {p4.x, p4.y, p4.z, p4.w};
    f16x4 o;
#pragma unroll
    for (int i = 0; i < 4; ++i) {
      float g = __logf(__fdividef(uu[i] + 1e-8f, 1.0f - uu[i] + 1e-8f));
      float z = (g + pp[i]) * rtau;
      float sig = __fdividef(1.0f, 1.0f + __expf(-z));
      o[i] = (_Float16)(-10000.0f * fmaxf(thr - sig, 0.0f) * 0.125f);
    }
    *(f16x4*)(mw + idx) = o;
  } else if (bx < 9216) {
    int gid = (bx - 8192) * 256 + threadIdx.x;
    int e8 = gid & 7;
    int tmp = gid >> 3;
    int h = tmp & 7;
    int bs = tmp >> 3;
    int s = bs & 1023;
    int b = bs >> 10;
    const float* src = kk + (size_t)gid * 8;
    float4 a = *(const float4*)src;
    float4 bq = *(const float4*)(src + 4);
    *(uint4v*)(kb + (((size_t)(b * 8 + h) * 1024 + s) * 64) + e8 * 8) =
        pack8_rne(a, bq);
  } else {
    int gid = (bx - 9216) * 256 + threadIdx.x;
    int s8 = gid & 127;
    int t1 = gid >> 7;
    int e = t1 & 63;
    int t2 = t1 >> 6;
    int h = t2 & 7;
    int b = t2 >> 3;
    float x[8];
#pragma unroll
    for (int j = 0; j < 8; ++j)
      x[j] = vv[((size_t)(b * 1024 + s8 * 8 + j) * 8 + h) * 64 + e];
    uint4v pv = pack8_rne(float4{x[0], x[1], x[2], x[3]},
                          float4{x[4], x[5], x[6], x[7]});
    *(uint4v*)(vT + ((size_t)(b * 8 + h) * 64 + e) * 1024 + s8 * 8) = pv;
  }
}

// ---------------- fused: 32 q-rows/block, MERGED q-tile QK ----------------
// 8 waves (512 thr). Wave w owns s-range [w*128, w*128+128). K fragments
// loaded ONCE and used for both 16-row q-tiles (accs[16] = 64 AGPR; Q is
// single bf16-RNE for both tiles -> fits the 128-reg/4-wave bucket, 2
// blocks/CU). 6 barriers. Then (R15 epilogue): coalesced NT att write from
// LDS, PV with vT fragments reused across q-tiles, partial reduce in reused
// att region, coalesced NT V store.
__global__ __launch_bounds__(512, 4) void k_fused(
    const float* __restrict__ q, const unsigned short* __restrict__ kb,
    const unsigned short* __restrict__ vT, const _Float16* __restrict__ mw,
    const int* __restrict__ p_causal, float* __restrict__ out) {
  int b, lb;
  decode_block(blockIdx.x, b, lb);
  const int h = blockIdx.y;
  const int tid = threadIdx.x;
  const int w = __builtin_amdgcn_readfirstlane(tid >> 6);  // 0..7
  const int c = tid & 63;
  const int cl = c & 15;
  const int cg = c >> 4;

  __shared__ __align__(16) unsigned char lds_att[32 * APITCH];  // 66 KB
  __shared__ float red0[2][8][16], redZ[2][8][16], redE[2][8][16];

  const int causal = p_causal[0];
  const unsigned short* kbb = kb + ((size_t)(b * 8 + h) * 1024) * 64;

  // ---- phase 0: stage 32 mask rows (64 KB) coalesced into LDS
  {
    const unsigned char* gmask =
        (const unsigned char*)(mw + ((size_t)h * LN + lb * 32) * SN);
    uint4v mk[8];
#pragma unroll
    for (int i = 0; i < 8; ++i)
      mk[i] = *(const uint4v*)(gmask + i * 8192 + tid * 16);
#pragma unroll
    for (int i = 0; i < 8; ++i) {
      int goff = i * 8192 + tid * 16;
      *(uint4v*)(lds_att + (goff >> 11) * APITCH + (goff & 2047)) = mk[i];
    }
  }

  // ---- Q fragments, single bf16 (RNE), both q-tiles
  uint4v qf[2][2];
#pragma unroll
  for (int qt = 0; qt < 2; ++qt)
#pragma unroll
    for (int cc = 0; cc < 2; ++cc) {
      const float* qp = q + (((size_t)b * LN + lb * 32 + qt * 16 + cl) * HN + h) * EN +
                        cc * 32 + cg * 8;
      float4 a = *(const float4*)qp;
      float4 bq = *(const float4*)(qp + 4);
      qf[qt][cc] = pack8_rne(a, bq);
    }

  __syncthreads();  // bar1: mask staged

  // ---- QK^T: K loaded ONCE per tile, MFMA'd against both q-tiles
  f32x4 accs[16];  // [qt*8 + tg]
#pragma unroll
  for (int tgb = 0; tgb < 2; ++tgb) {
    uint4v kf[4][2];
#pragma unroll
    for (int t2 = 0; t2 < 4; ++t2)
#pragma unroll
      for (int cc = 0; cc < 2; ++cc)
        kf[t2][cc] = *(const uint4v*)(kbb +
                                      (size_t)(w * 128 + (tgb * 4 + t2) * 16 + cl) * 64 +
                                      cc * 32 + cg * 8);
#pragma unroll
    for (int t2 = 0; t2 < 4; ++t2)
#pragma unroll
      for (int qt = 0; qt < 2; ++qt) {
        f32x4 acc = f32x4{0.f, 0.f, 0.f, 0.f};
#pragma unroll
        for (int cc = 0; cc < 2; ++cc)
          acc = __builtin_amdgcn_mfma_f32_16x16x32_bf16(
              __builtin_bit_cast(bf16x8, kf[t2][cc]),
              __builtin_bit_cast(bf16x8, qf[qt][cc]), acc, 0, 0, 0);
        accs[qt * 8 + tgb * 4 + t2] = acc;
      }
  }

  // ---- mask (LDS f16) + integer causal + max, both q-tiles
  float mx[2] = {-3.0e38f, -3.0e38f};
#pragma unroll
  for (int qt = 0; qt < 2; ++qt) {
    const int l = lb * 32 + qt * 16 + cl;
    const unsigned char* mrow = lds_att + (qt * 16 + cl) * APITCH;
#pragma unroll
    for (int tg = 0; tg < 8; ++tg) {
      const int s0 = w * 128 + tg * 16 + cg * 4;
      f16x4 m4 = *(const f16x4*)(mrow + s0 * 2);
#pragma unroll
      for (int r = 0; r < 4; ++r) {
        float v = fmaf(accs[qt * 8 + tg][r], 0.125f, (float)m4[r]);
        bool maskd = (causal != 0) && (s0 + r > l);
        v = maskd ? -1.0e30f : v;
        accs[qt * 8 + tg][r] = v;
        mx[qt] = fmaxf(mx[qt], v);
      }
    }
    mx[qt] = fmaxf(mx[qt], __shfl_xor(mx[qt], 16, 64));
    mx[qt] = fmaxf(mx[qt], __shfl_xor(mx[qt], 32, 64));
    if (cg == 0) red0[qt][w][cl] = mx[qt];
  }
  __syncthreads();  // bar2 (both q-tile maxes)

  float zz[2], ee[2];
#pragma unroll
  for (int qt = 0; qt < 2; ++qt) {
    float bmx = red0[qt][0][cl];
#pragma unroll
    for (int i = 1; i < 8; ++i) bmx = fmaxf(bmx, red0[qt][i][cl]);
    float z = 0.f, e = 0.f;
#pragma unroll
    for (int tg = 0; tg < 8; ++tg) {
#pragma unroll
      for (int r = 0; r < 4; ++r) {
        float tt = accs[qt * 8 + tg][r] - bmx;
        float ex = __expf(tt);
        z += ex;
        e = fmaf(ex, tt, e);  // ex==0 when masked: 0*finite = -0, no NaN
        accs[qt * 8 + tg][r] = ex;
      }
    }
    z += __shfl_xor(z, 16, 64);
    z += __shfl_xor(z, 32, 64);
    e += __shfl_xor(e, 16, 64);
    e += __shfl_xor(e, 32, 64);
    if (cg == 0) { redZ[qt][w][cl] = z; redE[qt][w][cl] = e; }
    zz[qt] = z; ee[qt] = e;
  }
  __syncthreads();  // bar3 (both q-tile sums)

#pragma unroll
  for (int qt = 0; qt < 2; ++qt) {
    const int l = lb * 32 + qt * 16 + cl;
    float Z = redZ[qt][0][cl], E = redE[qt][0][cl];
#pragma unroll
    for (int i = 1; i < 8; ++i) { Z += redZ[qt][i][cl]; E += redE[qt][i][cl]; }
    const float rz = __fdividef(1.0f, Z);
    if (w == 0 && cg == 0)
      out[OFF_ENT + ((size_t)b * HN + h) * LN + l] = __logf(Z) - E * rz;

    // normalized bf16 att into LDS (own row, own s-range — no hazard)
    unsigned char* arow = lds_att + (qt * 16 + cl) * APITCH;
#pragma unroll
    for (int tg = 0; tg < 8; ++tg) {
      const int s0 = w * 128 + tg * 16 + cg * 4;
      float ax = accs[qt * 8 + tg][0] * rz, ay = accs[qt * 8 + tg][1] * rz;
      float az = accs[qt * 8 + tg][2] * rz, aw = accs[qt * 8 + tg][3] * rz;
      uint2v pk = uint2v{rne2(ax, ay), rne2(az, aw)};
      *(uint2v*)(arow + s0 * 2) = pk;
    }
  }

  // ---- vT batch-0 prefetch (independent of LDS)
  const int et = w & 3, sh = w >> 2;
  const unsigned short* vbb =
      vT + ((size_t)(b * 8 + h) * 64 + et * 16 + cl) * 1024 + sh * 512;
  uint4v vf0[8];
#pragma unroll
  for (int j = 0; j < 8; ++j)
    vf0[j] = *(const uint4v*)(vbb + j * 32 + cg * 8);

  __syncthreads();  // bar4: full 32-row att tile visible

  // ---- coalesced NT fp32 att write: wave w -> rows w*4..w*4+3
  {
    float* abase = out + OFF_ATT + (((size_t)b * HN + h) * LN + lb * 32) * SN;
#pragma unroll
    for (int rr = 0; rr < 4; ++rr) {
      const int row = w * 4 + rr;
      const unsigned char* src = lds_att + row * APITCH;
      float* dst = abase + (size_t)row * SN;
#pragma unroll
      for (int it = 0; it < 4; ++it) {
        uint2v pk = *(const uint2v*)(src + it * 512 + c * 8);
        f32x4 o = f32x4{__uint_as_float(pk.x << 16),
                        __uint_as_float(pk.x & 0xffff0000u),
                        __uint_as_float(pk.y << 16),
                        __uint_as_float(pk.y & 0xffff0000u)};
        __builtin_nontemporal_store(o, (f32x4*)(dst + it * 256 + c * 4));
      }
    }
  }

  // ---- PV: wave w -> (e-tile et, s-half sh); each vT fragment used for
  // BOTH q-tiles. 32 MFMAs/wave.
  f32x4 acc00 = f32x4{0.f, 0.f, 0.f, 0.f}, acc01 = f32x4{0.f, 0.f, 0.f, 0.f};
  f32x4 acc10 = f32x4{0.f, 0.f, 0.f, 0.f}, acc11 = f32x4{0.f, 0.f, 0.f, 0.f};
#pragma unroll
  for (int scb = 0; scb < 2; ++scb) {
    uint4v vf[8];
    if (scb == 0) {
#pragma unroll
      for (int j = 0; j < 8; ++j) vf[j] = vf0[j];
    } else {
#pragma unroll
      for (int j = 0; j < 8; ++j)
        vf[j] = *(const uint4v*)(vbb + 256 + j * 32 + cg * 8);
    }
#pragma unroll
    for (int qt = 0; qt < 2; ++qt) {
      uint4v af[8];
#pragma unroll
      for (int j = 0; j < 8; ++j)
        af[j] = *(const uint4v*)(lds_att + (qt * 16 + cl) * APITCH +
                                 (sh * 512 + scb * 256 + j * 32 + cg * 8) * 2);
#pragma unroll
      for (int j = 0; j < 8; ++j) {
        bf16x8 a8 = __builtin_bit_cast(bf16x8, vf[j]);
        bf16x8 b8 = __builtin_bit_cast(bf16x8, af[j]);
        if (qt == 0) {
          if (j & 1)
            acc01 = __builtin_amdgcn_mfma_f32_16x16x32_bf16(a8, b8, acc01, 0, 0, 0);
          else
            acc00 = __builtin_amdgcn_mfma_f32_16x16x32_bf16(a8, b8, acc00, 0, 0, 0);
        } else {
          if (j & 1)
            acc11 = __builtin_amdgcn_mfma_f32_16x16x32_bf16(a8, b8, acc11, 0, 0, 0);
          else
            acc10 = __builtin_amdgcn_mfma_f32_16x16x32_bf16(a8, b8, acc10, 0, 0, 0);
        }
      }
    }
  }
  f32x4 sum0 = acc00 + acc01;
  f32x4 sum1 = acc10 + acc11;

  __syncthreads();  // bar5: all PV att reads done — att region reusable

  *(f32x4*)(lds_att + cl * APITCH + sh * 1024 + (et * 16 + cg * 4) * 4) = sum0;
  *(f32x4*)(lds_att + (16 + cl) * APITCH + sh * 1024 + (et * 16 + cg * 4) * 4) = sum1;

  __syncthreads();  // bar6: partials ready

  // ---- V: 2-way s-half reduce + coalesced NT store (512 thr = 32 r x 16 e4)
  {
    const int r = tid >> 4, e4 = tid & 15;
    f32x4 p0 = *(const f32x4*)(lds_att + r * APITCH + e4 * 16);
    f32x4 p1 = *(const f32x4*)(lds_att + r * APITCH + 1024 + e4 * 16);
    f32x4 s = p0 + p1;
    float* dst = out + (((size_t)b * LN + lb * 32 + r) * HN + h) * EN + e4 * 4;
    __builtin_nontemporal_store(s, (f32x4*)dst);
  }
}

extern "C" void kernel_launch(void* const* d_in, const int* in_sizes, int n_in,
                              void* d_out, int out_size, void* d_ws, size_t ws_size,
                              hipStream_t stream) {
  (void)in_sizes; (void)n_in; (void)out_size; (void)ws_size;
  const float* q   = (const float*)d_in[0];
  const float* k   = (const float*)d_in[1];
  const float* v   = (const float*)d_in[2];
  const float* phi = (const float*)d_in[4];
  const float* u   = (const float*)d_in[5];
  const float* lt  = (const float*)d_in[6];
  const float* th  = (const float*)d_in[7];
  const int*   cm  = (const int*)d_in[8];
  float* out = (float*)d_out;

  _Float16* mw = (_Float16*)((char*)d_ws + WS_MW);
  unsigned short* kb = (unsigned short*)((char*)d_ws + WS_KB);
  unsigned short* vT = (unsigned short*)((char*)d_ws + WS_VT);

  k_prep<<<dim3(10240), dim3(256), 0, stream>>>(k, v, phi, u, lt, th, mw, kb, vT);
  k_fused<<<dim3(128, 8, 1), dim3(512), 0, stream>>>(q, kb, vT, mw, cm, out);
}